// Round 1
// baseline (983.369 us; speedup 1.0000x reference)
//
#include <hip/hip_runtime.h>

#define LQ 8500
#define DM 256
#define NHEAD 8
#define NLVL 4
#define NPT 4

// ---------------------------------------------------------------------------
// Kernel 1: per-t1 frame sum  Xs[t1][n][i][c] = sum_{t2 in [t1-1,t1+1] & [0,4)} input[n][t2][i][c]
// ---------------------------------------------------------------------------
__global__ __launch_bounds__(256) void sum_frames(const float4* __restrict__ inp,
                                                  float4* __restrict__ Xs) {
    int g  = blockIdx.y;              // t1*2 + n
    int t1 = g >> 1, n = g & 1;
    int f  = blockIdx.x * 256 + threadIdx.x;   // [0, 8500*64) float4 units
    if (f >= LQ * 64) return;
    int t2a = t1 == 0 ? 0 : t1 - 1;
    int t2b = t1 == 3 ? 3 : t1 + 1;
    float4 s = {0.f, 0.f, 0.f, 0.f};
    for (int t2 = t2a; t2 <= t2b; ++t2) {
        float4 v = inp[(size_t)(n * 4 + t2) * (LQ * 64) + f];
        s.x += v.x; s.y += v.y; s.z += v.z; s.w += v.w;
    }
    Xs[(size_t)g * (LQ * 64) + f] = s;
}

// ---------------------------------------------------------------------------
// Kernel 2/4: generic fp32 GEMM, C[R x N] = A[R x 256] @ W[256 x N] + bias*scale(row)
// BM=64 BN=64 BK=32, 256 threads, 4x4 per thread.
// rows_per_group>0: bias scale selected by row/rows_per_group (for K(t1)*b_val).
// ---------------------------------------------------------------------------
__global__ __launch_bounds__(256) void gemm_k256(const float* __restrict__ A,
                                                 const float* __restrict__ W,
                                                 const float* __restrict__ bias,
                                                 float* __restrict__ C,
                                                 int R, int N, int rows_per_group,
                                                 float s0, float s1, float s2, float s3) {
    __shared__ float As[64][33];
    __shared__ float Ws[32][64];
    int tid = threadIdx.x;
    int tx = tid & 15, ty = tid >> 4;
    int r0 = blockIdx.x * 64, c0 = blockIdx.y * 64;
    float acc[4][4] = {};

    for (int k0 = 0; k0 < 256; k0 += 32) {
        // A tile 64x32
#pragma unroll
        for (int li = 0; li < 2; ++li) {
            int f = li * 256 + tid;
            int row = f >> 3, c4 = (f & 7) * 4;
            float4 v = {0.f, 0.f, 0.f, 0.f};
            if (r0 + row < R)
                v = *reinterpret_cast<const float4*>(&A[(size_t)(r0 + row) * 256 + k0 + c4]);
            As[row][c4 + 0] = v.x; As[row][c4 + 1] = v.y;
            As[row][c4 + 2] = v.z; As[row][c4 + 3] = v.w;
        }
        // W tile 32x64
#pragma unroll
        for (int li = 0; li < 2; ++li) {
            int f = li * 256 + tid;
            int row = f >> 4, c4 = (f & 15) * 4;
            float4 v = *reinterpret_cast<const float4*>(&W[(size_t)(k0 + row) * N + c0 + c4]);
            Ws[row][c4 + 0] = v.x; Ws[row][c4 + 1] = v.y;
            Ws[row][c4 + 2] = v.z; Ws[row][c4 + 3] = v.w;
        }
        __syncthreads();
#pragma unroll 8
        for (int kk = 0; kk < 32; ++kk) {
            float a0 = As[ty * 4 + 0][kk], a1 = As[ty * 4 + 1][kk];
            float a2 = As[ty * 4 + 2][kk], a3 = As[ty * 4 + 3][kk];
            float b0 = Ws[kk][tx * 4 + 0], b1 = Ws[kk][tx * 4 + 1];
            float b2 = Ws[kk][tx * 4 + 2], b3 = Ws[kk][tx * 4 + 3];
            acc[0][0] += a0 * b0; acc[0][1] += a0 * b1; acc[0][2] += a0 * b2; acc[0][3] += a0 * b3;
            acc[1][0] += a1 * b0; acc[1][1] += a1 * b1; acc[1][2] += a1 * b2; acc[1][3] += a1 * b3;
            acc[2][0] += a2 * b0; acc[2][1] += a2 * b1; acc[2][2] += a2 * b2; acc[2][3] += a2 * b3;
            acc[3][0] += a3 * b0; acc[3][1] += a3 * b1; acc[3][2] += a3 * b2; acc[3][3] += a3 * b3;
        }
        __syncthreads();
    }

    int col = c0 + tx * 4;
    float4 bv = *reinterpret_cast<const float4*>(&bias[col]);
#pragma unroll
    for (int i = 0; i < 4; ++i) {
        int row = r0 + ty * 4 + i;
        if (row >= R) continue;
        float sc = 1.f;
        if (rows_per_group > 0) {
            int gi = row / rows_per_group;
            sc = gi == 0 ? s0 : gi == 1 ? s1 : gi == 2 ? s2 : s3;
        }
        float4 o;
        o.x = acc[i][0] + bv.x * sc;
        o.y = acc[i][1] + bv.y * sc;
        o.z = acc[i][2] + bv.z * sc;
        o.w = acc[i][3] + bv.w * sc;
        *reinterpret_cast<float4*>(&C[(size_t)row * N + col]) = o;
    }
}

// ---------------------------------------------------------------------------
// Kernel 3: fused q-projection + softmax + deformable sampling.
// One block = 32 queries of one (t1, n). 256 threads.
// Phase A: stage q[32][256] in LDS; compute off (256 cols, all threads) and
//          att logits (128 cols, threads<128) as per-column register dots.
// Phase B: write locs (transformed off) + logits into LDS; softmax per (q,m);
//          bilinear sampling of Vs accumulating 32 channels per (q,m) thread.
// ---------------------------------------------------------------------------
__global__ __launch_bounds__(256) void proj_sample(const float* __restrict__ query,
                                                   const float* __restrict__ refp,
                                                   const float* __restrict__ Woff,
                                                   const float* __restrict__ boff,
                                                   const float* __restrict__ Watt,
                                                   const float* __restrict__ batt,
                                                   const float* __restrict__ Vs,
                                                   float* __restrict__ O) {
    __shared__ float sbuf[32 * 256];     // phase A: q staging; phase B: locs
    __shared__ float att_lds[32 * 128];
    __shared__ float refs[32 * 8];

    int tid = threadIdx.x;
    int qb = blockIdx.x, n = blockIdx.y, t1 = blockIdx.z;
    int q0 = qb * 32;
    int qcount = min(32, LQ - q0);

    // ---- stage q (zero-padded) ----
    const size_t qbase = ((size_t)(n * 4 + t1) * LQ + q0) * 256;
    float4* qs4 = reinterpret_cast<float4*>(sbuf);
#pragma unroll
    for (int it = 0; it < 8; ++it) {
        int f = it * 256 + tid;          // float4 index; row = f>>6
        int row = f >> 6;
        float4 v = {0.f, 0.f, 0.f, 0.f};
        if (row < qcount)
            v = *reinterpret_cast<const float4*>(&query[qbase + (size_t)row * 256 + (size_t)(f & 63) * 4]);
        qs4[f] = v;
    }
    // ---- stage reference points: refs[q][l*2+xy] ----
    {
        int row = tid >> 3, e = tid & 7;
        float v = 0.f;
        if (row < qcount)
            v = refp[((size_t)(n * 4 + t1) * LQ + q0 + row) * 8 + e];
        refs[row * 8 + e] = v;
    }
    __syncthreads();

    // ---- pass 1: off column tid (0..255) for all 32 queries ----
    float offacc[32];
    {
        float b = boff[tid];
#pragma unroll
        for (int q = 0; q < 32; ++q) offacc[q] = b;
        for (int k4 = 0; k4 < 64; ++k4) {
            float w0 = Woff[(size_t)(k4 * 4 + 0) * 256 + tid];
            float w1 = Woff[(size_t)(k4 * 4 + 1) * 256 + tid];
            float w2 = Woff[(size_t)(k4 * 4 + 2) * 256 + tid];
            float w3 = Woff[(size_t)(k4 * 4 + 3) * 256 + tid];
#pragma unroll
            for (int q = 0; q < 32; ++q) {
                float4 qv = qs4[q * 64 + k4];
                offacc[q] += qv.x * w0 + qv.y * w1 + qv.z * w2 + qv.w * w3;
            }
        }
    }
    // ---- pass 2: att logit column tid (threads < 128) ----
    float attacc[32];
    if (tid < 128) {
        float b = batt[tid];
#pragma unroll
        for (int q = 0; q < 32; ++q) attacc[q] = b;
        for (int k4 = 0; k4 < 64; ++k4) {
            float w0 = Watt[(size_t)(k4 * 4 + 0) * 128 + tid];
            float w1 = Watt[(size_t)(k4 * 4 + 1) * 128 + tid];
            float w2 = Watt[(size_t)(k4 * 4 + 2) * 128 + tid];
            float w3 = Watt[(size_t)(k4 * 4 + 3) * 128 + tid];
#pragma unroll
            for (int q = 0; q < 32; ++q) {
                float4 qv = qs4[q * 64 + k4];
                attacc[q] += qv.x * w0 + qv.y * w1 + qv.z * w2 + qv.w * w3;
            }
        }
    }
    // ---- transform off -> sampling location (still in registers) ----
    {
        int l = (tid >> 3) & 3, xy = tid & 1;
        float norm = (float)(80 >> l);   // W_l == H_l for these shapes
#pragma unroll
        for (int q = 0; q < 32; ++q)
            offacc[q] = refs[q * 8 + l * 2 + xy] + offacc[q] / norm;
    }
    __syncthreads();   // done reading q from sbuf

    // ---- phase B: publish locs + logits ----
#pragma unroll
    for (int q = 0; q < 32; ++q) sbuf[q * 256 + tid] = offacc[q];
    if (tid < 128) {
#pragma unroll
        for (int q = 0; q < 32; ++q) att_lds[q * 128 + tid] = attacc[q];
    }
    __syncthreads();

    // ---- softmax per (q, m) over 16 logits; scale by 1/K ----
    int sq = tid >> 3, sm = tid & 7;
    {
        float z[16];
#pragma unroll
        for (int j = 0; j < 16; ++j) z[j] = att_lds[sq * 128 + sm * 16 + j];
        float mx = z[0];
#pragma unroll
        for (int j = 1; j < 16; ++j) mx = fmaxf(mx, z[j]);
        float s = 0.f;
#pragma unroll
        for (int j = 0; j < 16; ++j) { z[j] = __expf(z[j] - mx); s += z[j]; }
        float Kc = (t1 == 0 || t1 == 3) ? 2.f : 3.f;
        float inv = 1.f / (s * Kc);
#pragma unroll
        for (int j = 0; j < 16; ++j) att_lds[sq * 128 + sm * 16 + j] = z[j] * inv;
    }
    // (no sync needed: same thread consumes its own 16 weights)

    // ---- sampling: thread (q, m) accumulates 32 channels ----
    float acc[32];
#pragma unroll
    for (int d = 0; d < 32; ++d) acc[d] = 0.f;

    if (sq < qcount) {
        const float* vbase = Vs + (size_t)(t1 * 2 + n) * LQ * 256 + sm * 32;
#pragma unroll
        for (int lp = 0; lp < 16; ++lp) {
            const int l = lp >> 2;
            const int WW = 80 >> l;
            const int HH = 80 >> l;
            const int start = (l == 0) ? 0 : (l == 1) ? 6400 : (l == 2) ? 8000 : 8400;
            int lc = ((sm * 4 + l) * 4 + (lp & 3)) * 2;
            float lx = sbuf[sq * 256 + lc + 0];
            float ly = sbuf[sq * 256 + lc + 1];
            float w = att_lds[sq * 128 + sm * 16 + lp];
            float x = lx * (float)WW - 0.5f;
            float y = ly * (float)HH - 0.5f;
            float x0f = floorf(x), y0f = floorf(y);
            int x0 = (int)x0f, y0 = (int)y0f;
            float wx1 = x - x0f, wx0 = 1.f - wx1;
            float wy1 = y - y0f, wy0 = 1.f - wy1;
#pragma unroll
            for (int cy = 0; cy < 2; ++cy) {
#pragma unroll
                for (int cx = 0; cx < 2; ++cx) {
                    int xi = x0 + cx, yi = y0 + cy;
                    if (xi >= 0 && xi < WW && yi >= 0 && yi < HH) {
                        float cw = w * (cx ? wx1 : wx0) * (cy ? wy1 : wy0);
                        const float4* vp = reinterpret_cast<const float4*>(
                            vbase + (size_t)(start + yi * WW + xi) * 256);
#pragma unroll
                        for (int d4 = 0; d4 < 8; ++d4) {
                            float4 v = vp[d4];
                            acc[d4 * 4 + 0] += cw * v.x;
                            acc[d4 * 4 + 1] += cw * v.y;
                            acc[d4 * 4 + 2] += cw * v.z;
                            acc[d4 * 4 + 3] += cw * v.w;
                        }
                    }
                }
            }
        }
        // ---- write O: row (n, t1, q), cols m*32.. ----
        size_t orow = (size_t)(n * 4 + t1) * LQ + q0 + sq;
        float4* op = reinterpret_cast<float4*>(O + orow * 256 + sm * 32);
#pragma unroll
        for (int d4 = 0; d4 < 8; ++d4) {
            float4 o;
            o.x = acc[d4 * 4 + 0]; o.y = acc[d4 * 4 + 1];
            o.z = acc[d4 * 4 + 2]; o.w = acc[d4 * 4 + 3];
            op[d4] = o;
        }
    }
}

// ---------------------------------------------------------------------------
extern "C" void kernel_launch(void* const* d_in, const int* in_sizes, int n_in,
                              void* d_out, int out_size, void* d_ws, size_t ws_size,
                              hipStream_t stream) {
    const float* query = (const float*)d_in[0];
    const float* refp  = (const float*)d_in[1];
    const float* inp   = (const float*)d_in[2];
    // d_in[3] spatial shapes, d_in[4] level starts: compile-time constants here
    const float* Woff = (const float*)d_in[5];
    const float* boff = (const float*)d_in[6];
    const float* Watt = (const float*)d_in[7];
    const float* batt = (const float*)d_in[8];
    const float* Wval = (const float*)d_in[9];
    const float* bval = (const float*)d_in[10];
    const float* Wout = (const float*)d_in[11];
    const float* bout = (const float*)d_in[12];
    float* out = (float*)d_out;

    const size_t R = (size_t)8 * LQ;           // 68000 rows
    float* Xs = (float*)d_ws;                  // 68000*256 f32 (later reused as O)
    float* Vs = Xs + R * 256;                  // 68000*256 f32

    // 1) per-t1 frame sums
    sum_frames<<<dim3((LQ * 64) / 256, 8), 256, 0, stream>>>(
        (const float4*)inp, (float4*)Xs);

    // 2) Vs = Xs @ W_val + K(t1)*b_val   (rows grouped per t1: 2*8500 each)
    gemm_k256<<<dim3((68000 + 63) / 64, 4), 256, 0, stream>>>(
        Xs, Wval, bval, Vs, 68000, 256, 2 * LQ, 2.f, 3.f, 3.f, 2.f);

    // 3) fused projection + softmax + sampling -> O (aliases Xs)
    proj_sample<<<dim3((LQ + 31) / 32, 2, 4), 256, 0, stream>>>(
        query, refp, Woff, boff, Watt, batt, Vs, Xs);

    // 4) d_out = O @ W_out + b_out
    gemm_k256<<<dim3((68000 + 63) / 64, 4), 256, 0, stream>>>(
        Xs, Wout, bout, out, 68000, 256, 0, 1.f, 1.f, 1.f, 1.f);
}

// Round 2
// 710.608 us; speedup vs baseline: 1.3838x; 1.3838x over previous
//
#include <hip/hip_runtime.h>

#define LQ 8500

__device__ __forceinline__ unsigned short f2bf(float f) {
    unsigned u = __float_as_uint(f);
    u += 0x7fffu + ((u >> 16) & 1u);
    return (unsigned short)(u >> 16);
}
__device__ __forceinline__ float blo(unsigned u) { return __uint_as_float(u << 16); }
__device__ __forceinline__ float bhi(unsigned u) { return __uint_as_float(u & 0xffff0000u); }

// ---------------------------------------------------------------------------
// Kernel 1: Xs[g=n*4+t1][i][c] = sum_{t2 in [t1-1,t1+1] cap [0,4)} input[n][t2][i][c]
// ---------------------------------------------------------------------------
__global__ __launch_bounds__(256) void sum_frames(const float4* __restrict__ inp,
                                                  float4* __restrict__ Xs) {
    int g = blockIdx.y;               // n*4 + t1
    int t1 = g & 3, n = g >> 2;
    int f = blockIdx.x * 256 + threadIdx.x;
    if (f >= LQ * 64) return;
    int t2a = t1 == 0 ? 0 : t1 - 1;
    int t2b = t1 == 3 ? 3 : t1 + 1;
    float4 s = {0.f, 0.f, 0.f, 0.f};
    for (int t2 = t2a; t2 <= t2b; ++t2) {
        float4 v = inp[(size_t)(n * 4 + t2) * (LQ * 64) + f];
        s.x += v.x; s.y += v.y; s.z += v.z; s.w += v.w;
    }
    Xs[(size_t)g * (LQ * 64) + f] = s;
}

// ---------------------------------------------------------------------------
// fp32 GEMM C[R x N] = A[R x 256] @ W[256 x N] + bias*scale; BF16 templ. output.
// scale selected by ((row / rows_per_group) & 3) when rows_per_group > 0.
// ---------------------------------------------------------------------------
template <int BF16OUT>
__global__ __launch_bounds__(256) void gemm_k256(const float* __restrict__ A,
                                                 const float* __restrict__ W,
                                                 const float* __restrict__ bias,
                                                 float* __restrict__ Cf,
                                                 ushort* __restrict__ Cb,
                                                 int R, int N, int rows_per_group,
                                                 float s0, float s1, float s2, float s3) {
    __shared__ float As[64][33];
    __shared__ float Ws[32][64];
    int tid = threadIdx.x;
    int tx = tid & 15, ty = tid >> 4;
    int r0 = blockIdx.x * 64, c0 = blockIdx.y * 64;
    float acc[4][4] = {};

    for (int k0 = 0; k0 < 256; k0 += 32) {
#pragma unroll
        for (int li = 0; li < 2; ++li) {
            int f = li * 256 + tid;
            int row = f >> 3, c4 = (f & 7) * 4;
            float4 v = {0.f, 0.f, 0.f, 0.f};
            if (r0 + row < R)
                v = *reinterpret_cast<const float4*>(&A[(size_t)(r0 + row) * 256 + k0 + c4]);
            As[row][c4 + 0] = v.x; As[row][c4 + 1] = v.y;
            As[row][c4 + 2] = v.z; As[row][c4 + 3] = v.w;
        }
#pragma unroll
        for (int li = 0; li < 2; ++li) {
            int f = li * 256 + tid;
            int row = f >> 4, c4 = (f & 15) * 4;
            float4 v = *reinterpret_cast<const float4*>(&W[(size_t)(k0 + row) * N + c0 + c4]);
            Ws[row][c4 + 0] = v.x; Ws[row][c4 + 1] = v.y;
            Ws[row][c4 + 2] = v.z; Ws[row][c4 + 3] = v.w;
        }
        __syncthreads();
#pragma unroll 8
        for (int kk = 0; kk < 32; ++kk) {
            float a0 = As[ty * 4 + 0][kk], a1 = As[ty * 4 + 1][kk];
            float a2 = As[ty * 4 + 2][kk], a3 = As[ty * 4 + 3][kk];
            float b0 = Ws[kk][tx * 4 + 0], b1 = Ws[kk][tx * 4 + 1];
            float b2 = Ws[kk][tx * 4 + 2], b3 = Ws[kk][tx * 4 + 3];
            acc[0][0] += a0 * b0; acc[0][1] += a0 * b1; acc[0][2] += a0 * b2; acc[0][3] += a0 * b3;
            acc[1][0] += a1 * b0; acc[1][1] += a1 * b1; acc[1][2] += a1 * b2; acc[1][3] += a1 * b3;
            acc[2][0] += a2 * b0; acc[2][1] += a2 * b1; acc[2][2] += a2 * b2; acc[2][3] += a2 * b3;
            acc[3][0] += a3 * b0; acc[3][1] += a3 * b1; acc[3][2] += a3 * b2; acc[3][3] += a3 * b3;
        }
        __syncthreads();
    }

    int col = c0 + tx * 4;
    float4 bv = *reinterpret_cast<const float4*>(&bias[col]);
#pragma unroll
    for (int i = 0; i < 4; ++i) {
        int row = r0 + ty * 4 + i;
        if (row >= R) continue;
        float sc = 1.f;
        if (rows_per_group > 0) {
            int gi = (row / rows_per_group) & 3;
            sc = gi == 0 ? s0 : gi == 1 ? s1 : gi == 2 ? s2 : s3;
        }
        float o0 = acc[i][0] + bv.x * sc;
        float o1 = acc[i][1] + bv.y * sc;
        float o2 = acc[i][2] + bv.z * sc;
        float o3 = acc[i][3] + bv.w * sc;
        if (BF16OUT) {
            ushort4 o;
            o.x = f2bf(o0); o.y = f2bf(o1); o.z = f2bf(o2); o.w = f2bf(o3);
            *reinterpret_cast<ushort4*>(&Cb[(size_t)row * N + col]) = o;
        } else {
            float4 o = {o0, o1, o2, o3};
            *reinterpret_cast<float4*>(&Cf[(size_t)row * N + col]) = o;
        }
    }
}

// ---------------------------------------------------------------------------
// Kernel 3: fused q-projection + softmax + bf16 deformable sampling.
// Block = 16 queries of one group g (flat grid, g = blockIdx.x & 7 -> XCD affinity).
// Phase A: stage q[16][256]; col-thread register GEMM for off(256) and att(128,
//          2 thr/col x 8 q). Phase B: locs+logits to LDS, softmax, gather.
// Thread in gather = (q, m, half): 16 fp32 channels from bf16 Vs.
// ---------------------------------------------------------------------------
__global__ __launch_bounds__(256) void proj_sample(const float* __restrict__ query,
                                                   const float* __restrict__ refp,
                                                   const float* __restrict__ Woff,
                                                   const float* __restrict__ boff,
                                                   const float* __restrict__ Watt,
                                                   const float* __restrict__ batt,
                                                   const ushort* __restrict__ Vs,
                                                   float* __restrict__ O) {
    __shared__ float sbuf[16 * 264];     // phase A: q staging (16x256 via float4); B: locs, stride 264
    __shared__ float att_lds[16 * 132];  // logits -> weights, stride 132
    __shared__ float refs[16 * 8];

    int tid = threadIdx.x;
    int bid = blockIdx.x;
    int g = bid & 7;                     // n*4 + t1
    int qb = bid >> 3;
    int t1 = g & 3;
    int q0 = qb * 16;
    int qcount = min(16, LQ - q0);

    // ---- stage q (zero-padded) ----
    const size_t qbase = ((size_t)g * LQ + q0) * 256;
    float4* qs4 = reinterpret_cast<float4*>(sbuf);
#pragma unroll
    for (int it = 0; it < 4; ++it) {
        int f = it * 256 + tid;          // float4 idx; row = f>>6
        int row = f >> 6;
        float4 v = {0.f, 0.f, 0.f, 0.f};
        if (row < qcount)
            v = *reinterpret_cast<const float4*>(&query[qbase + (size_t)row * 256 + (size_t)(f & 63) * 4]);
        qs4[f] = v;
    }
    if (tid < 128) {
        int row = tid >> 3, e = tid & 7;
        float v = 0.f;
        if (row < qcount)
            v = refp[((size_t)g * LQ + q0 + row) * 8 + e];
        refs[row * 8 + e] = v;
    }
    __syncthreads();

    // ---- pass 1: off column tid for 16 queries ----
    float offacc[16];
    {
        float b = boff[tid];
#pragma unroll
        for (int q = 0; q < 16; ++q) offacc[q] = b;
        for (int k4 = 0; k4 < 64; ++k4) {
            float w0 = Woff[(size_t)(k4 * 4 + 0) * 256 + tid];
            float w1 = Woff[(size_t)(k4 * 4 + 1) * 256 + tid];
            float w2 = Woff[(size_t)(k4 * 4 + 2) * 256 + tid];
            float w3 = Woff[(size_t)(k4 * 4 + 3) * 256 + tid];
#pragma unroll
            for (int q = 0; q < 16; ++q) {
                float4 qv = qs4[q * 64 + k4];
                offacc[q] += qv.x * w0 + qv.y * w1 + qv.z * w2 + qv.w * w3;
            }
        }
    }
    // ---- pass 2: att col (tid&127), queries qoff..qoff+8 ----
    float attacc[8];
    {
        int col = tid & 127;
        int qoff = (tid >> 7) * 8;
        float b = batt[col];
#pragma unroll
        for (int j = 0; j < 8; ++j) attacc[j] = b;
        for (int k4 = 0; k4 < 64; ++k4) {
            float w0 = Watt[(size_t)(k4 * 4 + 0) * 128 + col];
            float w1 = Watt[(size_t)(k4 * 4 + 1) * 128 + col];
            float w2 = Watt[(size_t)(k4 * 4 + 2) * 128 + col];
            float w3 = Watt[(size_t)(k4 * 4 + 3) * 128 + col];
#pragma unroll
            for (int j = 0; j < 8; ++j) {
                float4 qv = qs4[(qoff + j) * 64 + k4];
                attacc[j] += qv.x * w0 + qv.y * w1 + qv.z * w2 + qv.w * w3;
            }
        }
    }
    // ---- transform off -> pixel coords: x = ref*W + off - 0.5 ----
    {
        int l = (tid >> 3) & 3, xy = tid & 1;
        float Wl = (float)(80 >> l);
#pragma unroll
        for (int q = 0; q < 16; ++q)
            offacc[q] = refs[q * 8 + l * 2 + xy] * Wl + offacc[q] - 0.5f;
    }
    __syncthreads();   // done reading qs4

    // ---- publish locs + logits ----
#pragma unroll
    for (int q = 0; q < 16; ++q) sbuf[q * 264 + tid] = offacc[q];
    {
        int col = tid & 127;
        int qoff = (tid >> 7) * 8;
#pragma unroll
        for (int j = 0; j < 8; ++j) att_lds[(qoff + j) * 132 + col] = attacc[j];
    }
    __syncthreads();

    // ---- softmax per (q,m): threads 0..127 ----
    if (tid < 128) {
        int q = tid >> 3, m = tid & 7;
        float* a = &att_lds[q * 132 + m * 16];
        float z[16];
        float mx = -1e30f;
#pragma unroll
        for (int j = 0; j < 16; ++j) { z[j] = a[j]; mx = fmaxf(mx, z[j]); }
        float s = 0.f;
#pragma unroll
        for (int j = 0; j < 16; ++j) { z[j] = __expf(z[j] - mx); s += z[j]; }
        float Kc = (t1 == 0 || t1 == 3) ? 2.f : 3.f;
        float inv = 1.f / (s * Kc);
#pragma unroll
        for (int j = 0; j < 16; ++j) a[j] = z[j] * inv;
    }
    __syncthreads();

    // ---- gather: thread = (q, m, half), 16 channels ----
    int ql = tid >> 4, m = (tid >> 1) & 7, half = tid & 1;
    int q = q0 + ql;
    if (q < LQ) {
        const ushort* vb = Vs + (size_t)g * (LQ * 256) + m * 32 + half * 16;
        const float* lrow = &sbuf[ql * 264 + m * 32];
        const float* arow = &att_lds[ql * 132 + m * 16];
        float acc[16];
#pragma unroll
        for (int d = 0; d < 16; ++d) acc[d] = 0.f;

#pragma unroll 4
        for (int p = 0; p < 16; ++p) {
            const int l = p >> 2;
            const int Wl = 80 >> l;
            const int start = (l == 0) ? 0 : (l == 1) ? 6400 : (l == 2) ? 8000 : 8400;
            float x = lrow[p * 2 + 0];
            float y = lrow[p * 2 + 1];
            float w = arow[p];
            float x0f = floorf(x), y0f = floorf(y);
            int x0 = (int)x0f, y0 = (int)y0f;
            float wx1 = x - x0f, wx0 = 1.f - wx1;
            float wy1 = y - y0f, wy0 = 1.f - wy1;
#pragma unroll
            for (int cy = 0; cy < 2; ++cy) {
#pragma unroll
                for (int cx = 0; cx < 2; ++cx) {
                    int xi = x0 + cx, yi = y0 + cy;
                    bool valid = (xi >= 0) & (xi < Wl) & (yi >= 0) & (yi < Wl);
                    float cw = valid ? w * (cx ? wx1 : wx0) * (cy ? wy1 : wy0) : 0.f;
                    int xc = min(max(xi, 0), Wl - 1);
                    int yc = min(max(yi, 0), Wl - 1);
                    const uint4* vp = reinterpret_cast<const uint4*>(
                        vb + (size_t)(start + yc * Wl + xc) * 256);
                    uint4 a = vp[0];
                    uint4 b = vp[1];
                    acc[0]  += cw * blo(a.x); acc[1]  += cw * bhi(a.x);
                    acc[2]  += cw * blo(a.y); acc[3]  += cw * bhi(a.y);
                    acc[4]  += cw * blo(a.z); acc[5]  += cw * bhi(a.z);
                    acc[6]  += cw * blo(a.w); acc[7]  += cw * bhi(a.w);
                    acc[8]  += cw * blo(b.x); acc[9]  += cw * bhi(b.x);
                    acc[10] += cw * blo(b.y); acc[11] += cw * bhi(b.y);
                    acc[12] += cw * blo(b.z); acc[13] += cw * bhi(b.z);
                    acc[14] += cw * blo(b.w); acc[15] += cw * bhi(b.w);
                }
            }
        }
        float* op = O + ((size_t)g * LQ + q) * 256 + m * 32 + half * 16;
#pragma unroll
        for (int k = 0; k < 4; ++k) {
            float4 o = {acc[k * 4 + 0], acc[k * 4 + 1], acc[k * 4 + 2], acc[k * 4 + 3]};
            reinterpret_cast<float4*>(op)[k] = o;
        }
    }
}

// ---------------------------------------------------------------------------
extern "C" void kernel_launch(void* const* d_in, const int* in_sizes, int n_in,
                              void* d_out, int out_size, void* d_ws, size_t ws_size,
                              hipStream_t stream) {
    const float* query = (const float*)d_in[0];
    const float* refp  = (const float*)d_in[1];
    const float* inp   = (const float*)d_in[2];
    const float* Woff = (const float*)d_in[5];
    const float* boff = (const float*)d_in[6];
    const float* Watt = (const float*)d_in[7];
    const float* batt = (const float*)d_in[8];
    const float* Wval = (const float*)d_in[9];
    const float* bval = (const float*)d_in[10];
    const float* Wout = (const float*)d_in[11];
    const float* bout = (const float*)d_in[12];
    float* out = (float*)d_out;

    const size_t R = (size_t)8 * LQ;            // 68000 rows
    float* Xs = (float*)d_ws;                   // 69.6 MB, reused as O after value GEMM
    ushort* Vs = (ushort*)(Xs + R * 256);       // 34.8 MB bf16

    // 1) per-t1 frame sums (g = n*4+t1)
    sum_frames<<<dim3((LQ * 64 + 255) / 256, 8), 256, 0, stream>>>(
        (const float4*)inp, (float4*)Xs);

    // 2) Vs = bf16( Xs @ W_val + K(t1)*b_val ), groups of LQ rows, t1 = gi&3
    gemm_k256<1><<<dim3((68000 + 63) / 64, 4), 256, 0, stream>>>(
        Xs, Wval, bval, nullptr, Vs, 68000, 256, LQ, 2.f, 3.f, 3.f, 2.f);

    // 3) fused projection + softmax + sampling -> O (aliases Xs)
    proj_sample<<<dim3(((LQ + 15) / 16) * 8), 256, 0, stream>>>(
        query, refp, Woff, boff, Watt, batt, Vs, Xs);

    // 4) d_out = O @ W_out + b_out
    gemm_k256<0><<<dim3((68000 + 63) / 64, 4), 256, 0, stream>>>(
        Xs, Wout, bout, out, nullptr, 68000, 256, 0, 1.f, 1.f, 1.f, 1.f);
}